// Round 2
// baseline (728.470 us; speedup 1.0000x reference)
//
#include <hip/hip_runtime.h>
#include <hip/hip_bf16.h>
#include <stdint.h>

typedef __attribute__((ext_vector_type(8))) __bf16 bf16x8;
typedef __attribute__((ext_vector_type(4))) float f32x4;

__device__ __forceinline__ float bf2f(unsigned short u) {
  unsigned int x = ((unsigned int)u) << 16;
  float f; __builtin_memcpy(&f, &x, 4); return f;
}
__device__ __forceinline__ unsigned short f2bf(float f) {
  unsigned int x; __builtin_memcpy(&x, &f, 4);
  unsigned int r = x + 0x7fffu + ((x >> 16) & 1u);
  return (unsigned short)(r >> 16);
}
// pack two fp32 -> two bf16 (RNE), low = a, high = b
__device__ __forceinline__ unsigned int pk2(float a, float b) {
  __hip_bfloat162 h = __float22bfloat162_rn(float2{a, b});
  unsigned int u; __builtin_memcpy(&u, &h, 4); return u;
}
// convert 8 consecutive fp32 to 8 bf16 packed in a uint4
__device__ __forceinline__ uint4 cvt8(const float* src) {
  float4 a = *(const float4*)src;
  float4 b = *(const float4*)(src + 4);
  uint4 r;
  r.x = pk2(a.x, a.y); r.y = pk2(a.z, a.w);
  r.z = pk2(b.x, b.y); r.w = pk2(b.z, b.w);
  return r;
}

// async global -> LDS, 16B per lane. LDS dest = wave-uniform base + lane*16.
__device__ __forceinline__ void gload_lds16(const unsigned short* g, unsigned short* l) {
  __builtin_amdgcn_global_load_lds(
      (const __attribute__((address_space(1))) void*)g,
      (__attribute__((address_space(3))) void*)l, 16, 0, 0);
}

// ---------------------------------------------------------------------------
// One-shot fp32 -> bf16 conversion: x (12582912), Wqkv (3145728), Wo (2359296)
// grid = 8832 blocks x 256 threads x 8 elems = 18087936 elems exactly.
// ---------------------------------------------------------------------------
__global__ __launch_bounds__(256) void cvt_all(const float* __restrict__ x,
                                               const float* __restrict__ wqkv,
                                               const float* __restrict__ wo,
                                               unsigned short* __restrict__ xb,
                                               unsigned short* __restrict__ wqkvb,
                                               unsigned short* __restrict__ wob) {
  long i = ((long)blockIdx.x * 256 + threadIdx.x) * 8;
  if (i < 12582912) { *(uint4*)(xb + i) = cvt8(x + i); return; }
  i -= 12582912;
  if (i < 3145728) { *(uint4*)(wqkvb + i) = cvt8(wqkv + i); return; }
  i -= 3145728;
  *(uint4*)(wob + i) = cvt8(wo + i);
}

// ---------------------------------------------------------------------------
// GEMM: C[M,N] = A[M,K] @ W[N,K]^T (+ bias[N]).  A, W are bf16 (pre-converted).
// m97 structure: 128x128 tile, BK=32, 256 threads = 4 waves (2x2 of 64x64),
// mfma 16x16x32, staging via global_load_lds width=16 (4 insts/thread/K-step).
// Output fp32 (OUT_F32) or bf16. fp32 accumulate.
// ---------------------------------------------------------------------------
template <bool OUT_F32, bool HAS_BIAS>
__global__ __launch_bounds__(256) void gemm_bt(const unsigned short* __restrict__ A,
                                               const unsigned short* __restrict__ W,
                                               const float* __restrict__ bias,
                                               void* __restrict__ Cv,
                                               int M, int N, int K) {
  __shared__ __align__(16) unsigned short sA[128 * 32];
  __shared__ __align__(16) unsigned short sB[128 * 32];
  const int tid = threadIdx.x;
  const int lane = tid & 63;
  const int w = tid >> 6;
  const long m0 = (long)blockIdx.y * 128;
  const long n0 = (long)blockIdx.x * 128;
  const int wm = (w >> 1) * 64;
  const int wn = (w & 1) * 64;
  const int fr = lane & 15, fq = lane >> 4;

  // staging map: chunk c = j*256 + w*64 + lane covers row = c>>2, col = (c&3)*8
  const int srow = w * 16 + (lane >> 2);  // + j*64
  const int scol = (lane & 3) * 8;
  const unsigned short* Ag = A + m0 * K + (long)srow * K + scol;
  const unsigned short* Wg = W + n0 * K + (long)srow * K + scol;
  const long rstep = 64L * K;
  unsigned short* sAw = sA + w * 512;  // wave-uniform LDS base (w*1024 bytes)
  unsigned short* sBw = sB + w * 512;

  f32x4 acc[4][4];
#pragma unroll
  for (int i = 0; i < 4; ++i)
#pragma unroll
    for (int j = 0; j < 4; ++j) acc[i][j] = f32x4{0.f, 0.f, 0.f, 0.f};

  for (int k0 = 0; k0 < K; k0 += 32) {
    __syncthreads();
    gload_lds16(Ag + k0,         sAw);
    gload_lds16(Ag + rstep + k0, sAw + 2048);
    gload_lds16(Wg + k0,         sBw);
    gload_lds16(Wg + rstep + k0, sBw + 2048);
    __syncthreads();
    bf16x8 af[4], bfr[4];
#pragma unroll
    for (int t = 0; t < 4; ++t) {
      af[t]  = *(const bf16x8*)&sA[(wm + t * 16 + fr) * 32 + fq * 8];
      bfr[t] = *(const bf16x8*)&sB[(wn + t * 16 + fr) * 32 + fq * 8];
    }
#pragma unroll
    for (int mt = 0; mt < 4; ++mt)
#pragma unroll
      for (int nt = 0; nt < 4; ++nt)
        acc[mt][nt] = __builtin_amdgcn_mfma_f32_16x16x32_bf16(af[mt], bfr[nt], acc[mt][nt], 0, 0, 0);
  }

#pragma unroll
  for (int nt = 0; nt < 4; ++nt) {
    long n = n0 + wn + nt * 16 + fr;
    float bv = HAS_BIAS ? bias[n] : 0.f;
#pragma unroll
    for (int mt = 0; mt < 4; ++mt)
#pragma unroll
      for (int r = 0; r < 4; ++r) {
        long m = m0 + wm + mt * 16 + fq * 4 + r;
        float v = acc[mt][nt][r] + bv;
        if (OUT_F32)
          ((float*)Cv)[m * N + n] = v;
        else
          ((unsigned short*)Cv)[m * N + n] = f2bf(v);
      }
  }
}

// ---------------------------------------------------------------------------
// RoPE (in-place on bf16 qkv_ws) + fp32 KV cache scatter — fully vectorized.
// Work units of 8 elements:
//   u in [0, 917504): RoPE pair-groups. token m = u/112, g = u%112,
//     head = g>>3 (0..13: 12 q + 2 k), d0 = (g&7)*8 (first-half dim offset).
//   u in [917504, 1179648): v-copy groups. m = u2/32, g = u2&31.
// grid = 4608 * 256 = 1179648 units exactly.
// ---------------------------------------------------------------------------
__global__ __launch_bounds__(256) void rope_scatter(unsigned short* __restrict__ qkv,
                                                    const float* __restrict__ cosb,
                                                    const float* __restrict__ sinb,
                                                    const int* __restrict__ slot_mapping,
                                                    float* __restrict__ kc,
                                                    float* __restrict__ vc) {
  const int u = blockIdx.x * 256 + threadIdx.x;
  if (u < 917504) {
    const int m = u / 112;
    const int g = u - m * 112;
    const int head = g >> 3;
    const int d0 = (g & 7) * 8;
    const int slot = slot_mapping[m];
    const size_t base = (size_t)m * 2048;
    const size_t cbase = (size_t)m * 128;
    const int off = head < 12 ? head * 128 : 1536 + (head - 12) * 128;

    union { uint4 q; unsigned short s[8]; } X1, X2, O1, O2;
    X1.q = *(const uint4*)(qkv + base + off + d0);
    X2.q = *(const uint4*)(qkv + base + off + d0 + 64);
    float c1[8], s1[8], c2[8], s2[8];
    *(float4*)&c1[0] = *(const float4*)(cosb + cbase + d0);
    *(float4*)&c1[4] = *(const float4*)(cosb + cbase + d0 + 4);
    *(float4*)&s1[0] = *(const float4*)(sinb + cbase + d0);
    *(float4*)&s1[4] = *(const float4*)(sinb + cbase + d0 + 4);
    *(float4*)&c2[0] = *(const float4*)(cosb + cbase + d0 + 64);
    *(float4*)&c2[4] = *(const float4*)(cosb + cbase + d0 + 68);
    *(float4*)&s2[0] = *(const float4*)(sinb + cbase + d0 + 64);
    *(float4*)&s2[4] = *(const float4*)(sinb + cbase + d0 + 68);

    float o1[8], o2[8];
#pragma unroll
    for (int j = 0; j < 8; ++j) {
      float x1 = bf2f(X1.s[j]), x2 = bf2f(X2.s[j]);
      o1[j] = x1 * c1[j] - x2 * s1[j];
      o2[j] = x2 * c2[j] + x1 * s2[j];
      O1.s[j] = f2bf(o1[j]);
      O2.s[j] = f2bf(o2[j]);
    }
    *(uint4*)(qkv + base + off + d0) = O1.q;
    *(uint4*)(qkv + base + off + d0 + 64) = O2.q;
    if (head >= 12) {
      float* kp = kc + (size_t)slot * 256 + (head - 12) * 128 + d0;
      *(float4*)(kp)      = *(const float4*)&o1[0];
      *(float4*)(kp + 4)  = *(const float4*)&o1[4];
      *(float4*)(kp + 64) = *(const float4*)&o2[0];
      *(float4*)(kp + 68) = *(const float4*)&o2[4];
    }
  } else {
    const int u2 = u - 917504;
    const int m = u2 >> 5;
    const int g = u2 & 31;
    const int slot = slot_mapping[m];
    union { uint4 q; unsigned short s[8]; } V;
    V.q = *(const uint4*)(qkv + (size_t)m * 2048 + 1792 + g * 8);
    float vo[8];
#pragma unroll
    for (int j = 0; j < 8; ++j) vo[j] = bf2f(V.s[j]);
    float* vp = vc + (size_t)slot * 256 + g * 8;
    *(float4*)(vp)     = *(const float4*)&vo[0];
    *(float4*)(vp + 4) = *(const float4*)&vo[4];
  }
}

// ---------------------------------------------------------------------------
// Flash attention, causal, GQA (12 q-heads over 2 kv-heads). All-bf16 internal.
// Block = (qb, h, b): 64 Q rows, 4 waves x 16 rows; KV tiles of 64.
// K staged via global_load_lds with swizzle moved to the global source addr.
// ---------------------------------------------------------------------------
__global__ __launch_bounds__(256) void attn_kernel(const unsigned short* __restrict__ qkv,
                                                   unsigned short* __restrict__ out) {
  const int qb = blockIdx.x, h = blockIdx.y, b = blockIdx.z;
  const int kvh = h / 6;
  __shared__ __align__(16) unsigned short sK[64 * 128];
  __shared__ __align__(16) unsigned short sV[128 * 72];
  __shared__ __align__(16) unsigned short sP[4][16 * 72];
  const int tid = threadIdx.x, lane = tid & 63, w = tid >> 6;
  const int fr = lane & 15, fq = lane >> 4;
  const float scale = 0.08838834764831845f;
  const float LOG2E = 1.44269504089f;

  bf16x8 qf[4];
  {
    const unsigned short* qp =
        qkv + ((size_t)(b * 2048 + qb * 64 + w * 16 + fr) * 2048 + h * 128 + fq * 8);
#pragma unroll
    for (int kt = 0; kt < 4; ++kt) qf[kt] = *(const bf16x8*)(qp + kt * 32);
  }
  float m_i[4], l_i[4];
#pragma unroll
  for (int r = 0; r < 4; ++r) { m_i[r] = -3.0e38f; l_i[r] = 0.f; }
  f32x4 accO[8];
#pragma unroll
  for (int i = 0; i < 8; ++i) accO[i] = f32x4{0.f, 0.f, 0.f, 0.f};

  for (int t = 0; t <= qb; ++t) {
    __syncthreads();
    const size_t tok0 = (size_t)(b * 2048 + t * 64);
    // K: global_load_lds, swizzle pre-applied on global source (m173 pattern).
    // LDS chunk c = i*256 + w*64 + lane -> kv = c>>4, gp = c&15, g = gp^(kv&7)
#pragma unroll
    for (int i = 0; i < 4; ++i) {
      int c = i * 256 + w * 64 + lane;
      int kv = c >> 4, gp = c & 15;
      int g = gp ^ (kv & 7);
      gload_lds16(qkv + (tok0 + kv) * 2048 + 1536 + kvh * 128 + g * 8,
                  sK + i * 2048 + w * 512);
    }
#pragma unroll
    for (int i = 0; i < 4; ++i) {
      int idx = i * 256 + tid;
      int kv = idx >> 4;
      int d0 = (idx & 15) * 8;
      union { uint4 q; unsigned short u[8]; } cv;
      cv.q = *(const uint4*)(qkv + (tok0 + kv) * 2048 + 1792 + kvh * 128 + d0);
#pragma unroll
      for (int jj = 0; jj < 8; ++jj) {
        int j = (jj + lane) & 7;
        sV[(d0 + j) * 72 + kv] = cv.u[j];
      }
    }
    __syncthreads();

    f32x4 s4[4];
#pragma unroll
    for (int nt = 0; nt < 4; ++nt) s4[nt] = f32x4{0.f, 0.f, 0.f, 0.f};
    __builtin_amdgcn_s_setprio(1);
#pragma unroll
    for (int nt = 0; nt < 4; ++nt) {
      int kvl = nt * 16 + fr;
      int swz = kvl & 7;
#pragma unroll
      for (int kt = 0; kt < 4; ++kt) {
        bf16x8 kf = *(const bf16x8*)&sK[kvl * 128 + ((kt * 4 + fq) ^ swz) * 8];
        s4[nt] = __builtin_amdgcn_mfma_f32_16x16x32_bf16(qf[kt], kf, s4[nt], 0, 0, 0);
      }
    }
    __builtin_amdgcn_s_setprio(0);
    float sc[4][4];
    const bool diag = (t == qb);
#pragma unroll
    for (int nt = 0; nt < 4; ++nt)
#pragma unroll
      for (int r = 0; r < 4; ++r) {
        float v = s4[nt][r] * scale;
        if (diag && (nt * 16 + fr > w * 16 + fq * 4 + r)) v = -1e30f;
        sc[nt][r] = v;
      }
    float pm[4][4];
#pragma unroll
    for (int r = 0; r < 4; ++r) {
      float mx = fmaxf(fmaxf(sc[0][r], sc[1][r]), fmaxf(sc[2][r], sc[3][r]));
#pragma unroll
      for (int off = 1; off < 16; off <<= 1) mx = fmaxf(mx, __shfl_xor(mx, off));
      float mnew = fmaxf(m_i[r], mx);
      float al = exp2f((m_i[r] - mnew) * LOG2E);
      float rs = 0.f;
#pragma unroll
      for (int nt = 0; nt < 4; ++nt) {
        float p = exp2f((sc[nt][r] - mnew) * LOG2E);
        pm[nt][r] = p;
        rs += p;
      }
#pragma unroll
      for (int off = 1; off < 16; off <<= 1) rs += __shfl_xor(rs, off);
      l_i[r] = l_i[r] * al + rs;
      m_i[r] = mnew;
#pragma unroll
      for (int n2 = 0; n2 < 8; ++n2) accO[n2][r] *= al;
    }
#pragma unroll
    for (int nt = 0; nt < 4; ++nt)
#pragma unroll
      for (int r = 0; r < 4; ++r)
        sP[w][(fq * 4 + r) * 72 + nt * 16 + fr] = f2bf(pm[nt][r]);
    __builtin_amdgcn_s_setprio(1);
#pragma unroll
    for (int kt = 0; kt < 2; ++kt) {
      bf16x8 pf = *(const bf16x8*)&sP[w][fr * 72 + kt * 32 + fq * 8];
#pragma unroll
      for (int n2 = 0; n2 < 8; ++n2) {
        bf16x8 vf = *(const bf16x8*)&sV[(n2 * 16 + fr) * 72 + kt * 32 + fq * 8];
        accO[n2] = __builtin_amdgcn_mfma_f32_16x16x32_bf16(pf, vf, accO[n2], 0, 0, 0);
      }
    }
    __builtin_amdgcn_s_setprio(0);
  }

#pragma unroll
  for (int r = 0; r < 4; ++r) {
    float inv = 1.f / l_i[r];
    size_t row = (size_t)(b * 2048 + qb * 64 + w * 16 + fq * 4 + r);
#pragma unroll
    for (int n2 = 0; n2 < 8; ++n2)
      out[row * 1536 + h * 128 + n2 * 16 + fr] = f2bf(accO[n2][r] * inv);
  }
}

// ---------------------------------------------------------------------------
extern "C" void kernel_launch(void* const* d_in, const int* in_sizes, int n_in,
                              void* d_out, int out_size, void* d_ws, size_t ws_size,
                              hipStream_t stream) {
  const float* x    = (const float*)d_in[0];
  const float* cosb = (const float*)d_in[1];
  const float* sinb = (const float*)d_in[2];
  const float* kci  = (const float*)d_in[3];
  const float* vci  = (const float*)d_in[4];
  const int* slot   = (const int*)d_in[5];
  const float* Wqkv = (const float*)d_in[6];
  const float* bqkv = (const float*)d_in[7];
  const float* Wo   = (const float*)d_in[8];

  float* out = (float*)d_out;
  float* kc  = out + (size_t)12582912;   // 4*2048*1536
  float* vc  = kc + (size_t)4194304;     // 16384*2*128

  unsigned short* qkv_ws  = (unsigned short*)d_ws;       // 8192*2048 bf16
  unsigned short* attn_ws = qkv_ws + (size_t)16777216;   // 8192*1536 bf16
  unsigned short* xb      = attn_ws;                     // alias: x_bf16 dead before attn writes
  unsigned short* wqkvb   = attn_ws + (size_t)12582912;  // 2048*1536 bf16
  unsigned short* wob     = wqkvb + (size_t)3145728;     // 1536*1536 bf16

  // kv caches: reference scatters into the (zero) input caches
  hipMemcpyAsync(kc, kci, (size_t)4194304 * 4, hipMemcpyDeviceToDevice, stream);
  hipMemcpyAsync(vc, vci, (size_t)4194304 * 4, hipMemcpyDeviceToDevice, stream);

  // 0) fp32 -> bf16 pre-convert: x, Wqkv, Wo
  cvt_all<<<dim3(8832), 256, 0, stream>>>(x, Wqkv, Wo, xb, wqkvb, wob);
  // 1) qkv = x @ Wqkv^T + b   (bf16 in, bf16 internal out)
  gemm_bt<false, true><<<dim3(16, 64), 256, 0, stream>>>(
      xb, wqkvb, bqkv, qkv_ws, 8192, 2048, 1536);
  // 2) RoPE q,k in place + scatter k,v into fp32 caches (vectorized)
  rope_scatter<<<dim3(4608), 256, 0, stream>>>(qkv_ws, cosb, sinb, slot, kc, vc);
  // 3) causal GQA flash attention (bf16 internal)
  attn_kernel<<<dim3(32, 12, 4), 256, 0, stream>>>(qkv_ws, attn_ws);
  // 4) out = attn @ Wo^T   (bf16 internal in, fp32 out)
  gemm_bt<true, false><<<dim3(12, 64), 256, 0, stream>>>(
      attn_ws, wob, nullptr, out, 8192, 1536, 1536);
}